// Round 9
// baseline (21.310 us; speedup 1.0000x reference)
//
#include <hip/hip_runtime.h>

#define NK 16   // cluster centers
#define E  4    // f32x4 elements per thread (n4 = 3136 * 1024 exactly)

typedef float f32x4 __attribute__((ext_vector_type(4)));

// Bit-exact replica of the reference's per-element assignment for ANY t:
// scan k ascending, strict <  -> first index wins ties (jnp.argmin semantics).
__device__ __forceinline__ float argmin16(float t, const float* cen) {
    float best = 3.4e38f;
    float bc = 0.0f;
#pragma unroll
    for (int k = 0; k < NK; ++k) {
        float d = fabsf(t - cen[k]);
        bool p = d < best;
        best = p ? d : best;
        bc   = p ? cen[k] : bc;
    }
    return bc;
}

// No min-waves bound (R7's (256,8) cap spilled the prefetch regs to scratch).
// E=4 prefetch (16 VGPR) + working set ~= 55 VGPR < 64 -> full 8 waves/SIMD.
__global__ __launch_bounds__(256) void lutfq_kernel(
    const f32x4* __restrict__ x,
    const float* __restrict__ scales,
    const float* __restrict__ centers,
    f32x4*       __restrict__ out,
    int n4)
{
    __shared__ float s_lut[512];  // bucket -> center over u2 = 2t

    const int tid = threadIdx.x;
    // Block-contiguous: block owns [blockIdx*1024, blockIdx*1024 + 1024).
    const int i0 = blockIdx.x * (256 * E) + tid;

    // ---- Issue ALL four streaming loads FIRST (4-deep MLP per wave); the
    // whole prologue (center rint, scale math, LUT build) hides their flight.
    f32x4 v[E];
#pragma unroll
    for (int u = 0; u < E; ++u) {
        int i = i0 + u * 256;
        v[u] = (i < n4) ? x[i] : f32x4{0.f, 0.f, 0.f, 0.f};
    }

    // Rounded centers in wave-uniform registers.
    float cen[NK];
#pragma unroll
    for (int k = 0; k < NK; ++k) cen[k] = rintf(centers[k]);  // round-half-to-even

    // Per-thread channels invariant: all i === tid (mod 64). Load scales once.
    const int c4 = (tid & 63) * 4;
    const f32x4 sv = *reinterpret_cast<const f32x4*>(&scales[c4]);
    float den[4], r256[4], so[4];
#pragma unroll
    for (int j = 0; j < 4; ++j) {
        den[j]  = sv[j] + 1e-8f;        // ref's denominator
        r256[j] = 256.0f / den[j];      // fast-path reciprocal (<=1 ulp on u2)
        so[j]   = sv[j] * 0.0078125f;   // s/128, exact
    }

    // 512-bucket LUT over u2 = 2t; integer centers -> decision midpoints are
    // half-integers = bucket edges -> constant on bucket interiors. Buckets
    // 0 / >=510 built at their LEFT edge (t=-128/127): provably never a
    // midpoint of distinct integer centers in [-128,127] -> the clip masses
    // are served exactly with no fallback.
    for (int ub = tid; ub < 512; ub += 256) {
        float t;
        if (ub == 0)        t = -128.0f;
        else if (ub >= 510) t = 127.0f;
        else                t = 0.5f * (float)(ub - 256) + 0.25f;
        s_lut[ub] = argmin16(t, cen);
    }
    __syncthreads();

    auto process = [&](f32x4 xv) -> f32x4 {
        f32x4 r;
#pragma unroll
        for (int j = 0; j < 4; ++j) {
            // u2 = 2 * clip(x/(s+eps)*128, -128, 127) as one mul + clamp.
            float u2 = xv[j] * r256[j];
            u2 = fminf(fmaxf(u2, -256.0f), 254.0f);

            float fl   = floorf(u2);      // exact
            float frac = u2 - fl;
            int   ub   = (int)fl + 256;   // 0..510

            float c = s_lut[ub];

            // Edge band (reciprocal's <=2^-15 error + ref's rounded-distance
            // tie band), minus the provably-safe clamp rails: replay exact
            // ref arithmetic. ~5e-4 of elements, exec-masked.
            bool band = (frac < 0x1p-12f) | (frac > 1.0f - 0x1p-12f);
            bool rail = (u2 == -256.0f) | (u2 == 254.0f);
            if (band && !rail) {
                float t = (xv[j] / den[j]) * 128.0f;
                t = fminf(fmaxf(t, -128.0f), 127.0f);
                c = argmin16(t, cen);                   // bit-exact ref replay
            }
            r[j] = c * so[j];   // c*(s/128) == (c/128)*s bit-exactly
        }
        return r;
    };

    // Process + nontemporal store: writes bypass L2/L3 allocation (straight
    // to HBM drain) and keep x L3-resident across graph replays. Loads stay
    // cached on purpose (R4's both-streams-nt was flat).
#pragma unroll
    for (int u = 0; u < E; ++u) {
        int i = i0 + u * 256;
        f32x4 r = process(v[u]);
        if (i < n4) __builtin_nontemporal_store(r, &out[i]);
    }
}

extern "C" void kernel_launch(void* const* d_in, const int* in_sizes, int n_in,
                              void* d_out, int out_size, void* d_ws, size_t ws_size,
                              hipStream_t stream) {
    const float* x       = (const float*)d_in[0];
    const float* scales  = (const float*)d_in[1];
    const float* centers = (const float*)d_in[2];
    float* out = (float*)d_out;

    int n4 = out_size / 4;                          // 3,211,264 here
    int per_block = 256 * E;                        // 1024
    int blocks = (n4 + per_block - 1) / per_block;  // 3136

    lutfq_kernel<<<blocks, 256, 0, stream>>>(
        (const f32x4*)x, scales, centers, (f32x4*)out, n4);
}